// Round 12
// baseline (267.160 us; speedup 1.0000x reference)
//
#include <hip/hip_runtime.h>

// irreps: 256x0e + 128x1e + 64x2e ; x row = 960 fp32
// R12: persistent blocks + LDS double-buffer pipeline (T14, sized to fit regs):
//   tile t: write_stage(cur) | BAR | issue(t+NB) loads (fly across all compute)
//           GEMM1(cur) | BAR | normact->cur | BAR | GEMM2(cur) | store | swap
// Stage regs <= 32 VGPR (l0 ROWS=32, l1/l2 ROWS=16); __launch_bounds__(256,3)
// leaves VGPR headroom (R4/R6 scratch disasters were the 64-VGPR clamp from
// (256,4)). 3 barriers/tile; buffer alternation makes the 4th unnecessary.

typedef __bf16 v8bf  __attribute__((ext_vector_type(8)));
typedef __bf16 v2bf  __attribute__((ext_vector_type(2)));
typedef float  v4f   __attribute__((ext_vector_type(4)));

__device__ __forceinline__ unsigned short bfbits(float x) {
    __bf16 h = (__bf16)x;
    return __builtin_bit_cast(unsigned short, h);
}

// Phi(n) = 0.5*(1+erf(n/sqrt(2))) = gelu(n)/n, n>=0.  A&S 7.1.26.
__device__ __forceinline__ float phi_from_n(float n) {
    float z = n * 0.70710678118654752f;
    float t = __builtin_amdgcn_rcpf(fmaf(0.3275911f, z, 1.0f));
    float p = t * fmaf(t, fmaf(t, fmaf(t, fmaf(t, 1.061405429f, -1.453152027f),
                                       1.421413741f), -0.284496736f), 0.254829592f);
    float e = __builtin_amdgcn_exp2f(z * z * -1.4426950408889634f);
    return fmaf(p * e, -0.5f, 1.0f);
}

// --- pre-pass: W[u][w] fp32 -> WT[w][u] bf16, scaled by 1/sqrt(mul_in) -------
__global__ __launch_bounds__(256) void wt_prep(
    const float* __restrict__ w0, const float* __restrict__ w1,
    const float* __restrict__ w2, const float* __restrict__ w3,
    const float* __restrict__ w4, const float* __restrict__ w5,
    unsigned short* __restrict__ out)
{
    int t = blockIdx.x * 256 + threadIdx.x;
    if (t >= 172032) return;
    int s = (t < 65536) ? 0 : (t < 81920) ? 1 : (t < 86016) ? 2
          : (t < 151552) ? 3 : (t < 167936) ? 4 : 5;
    int base = (s == 0) ? 0 : (s == 1) ? 65536 : (s == 2) ? 81920
             : (s == 3) ? 86016 : (s == 4) ? 151552 : 167936;
    int lg   = (s == 0 || s == 3) ? 8 : (s == 1 || s == 4) ? 7 : 6;
    float scl = (s == 0 || s == 3) ? 0.0625f
              : (s == 1 || s == 4) ? 0.08838834764831845f : 0.125f;
    const float* p = (s == 0) ? w0 : (s == 1) ? w1 : (s == 2) ? w2
                   : (s == 3) ? w3 : (s == 4) ? w4 : w5;
    int loc = t - base;
    int w = loc >> lg;
    int u = loc & ((1 << lg) - 1);
    out[t] = bfbits(p[(u << lg) + w] * scl);
}

// --- persistent per-irrep pipelined worker -----------------------------------
// LDS (per buffer): bf16 planes [i][n(ROWS)][u(U)], XOR-swizzle ^((R&7)<<3),
// R = i*ROWS+n.  Elem counts: l0 8192, l1 6144, l2 5120 (buffer = 8192).
template<int U, int D, int OFF, int ROWS>
__device__ __forceinline__ void irrep_pipe(
    const float* __restrict__ x,
    const unsigned short* __restrict__ wt0,
    const unsigned short* __restrict__ wt1,
    float* __restrict__ out,
    unsigned short* lds0, unsigned short* lds1,
    int bid, int NB)
{
    constexpr int NT   = 65536 / ROWS;
    constexpr int MT   = (ROWS * D) / 16;
    constexpr int NPW  = U / 64;
    constexpr int KT   = U / 32;
    constexpr int NR16 = ROWS / 16;
    constexpr int SIT  = (D == 1) ? (ROWS * (U / 8)) / 256
                                  : (ROWS * (U / 2)) / 256;
    static_assert(ROWS * D * U <= 8192, "LDS overflow");

    const int tid  = threadIdx.x;
    const int lane = tid & 63;
    const int wid  = tid >> 6;
    const int wcol = lane & 15;
    const int kcol = (lane >> 4) << 3;
    const int g4   = (lane >> 4) << 2;

    // raw x prefetch regs (one tile), statically indexed, <=32 VGPR
    float4 s4[(D == 1) ? 2 * SIT : 1];
    float2 s2[(D  > 1) ? SIT * D : 1];

    auto issue = [&](int tile) {
        if constexpr (D == 1) {
            #pragma unroll
            for (int o = 0; o < SIT; ++o) {
                int oct = o * 256 + tid;
                int row = oct / (U / 8);
                int u0  = (oct % (U / 8)) * 8;
                const float4* p = reinterpret_cast<const float4*>(
                    x + (long)(tile * ROWS + row) * 960 + OFF + u0);
                s4[2 * o]     = p[0];
                s4[2 * o + 1] = p[1];
            }
        } else {
            constexpr int PAIRS = U / 2;
            #pragma unroll
            for (int g = 0; g < SIT; ++g) {
                int gid = g * 256 + tid;
                int row = gid / PAIRS;
                int u0  = (gid % PAIRS) * 2;
                const float2* p = reinterpret_cast<const float2*>(
                    x + (long)(tile * ROWS + row) * 960 + OFF + u0 * D);
                #pragma unroll
                for (int j = 0; j < D; ++j) s2[g * D + j] = p[j];
            }
        }
    };

    auto write_stage = [&](unsigned short* buf) {
        if constexpr (D == 1) {
            #pragma unroll
            for (int o = 0; o < SIT; ++o) {
                int oct = o * 256 + tid;
                int row = oct / (U / 8);
                int u0  = (oct % (U / 8)) * 8;
                float4 fa = s4[2 * o], fb = s4[2 * o + 1];
                v8bf hv = { (__bf16)fa.x, (__bf16)fa.y, (__bf16)fa.z, (__bf16)fa.w,
                            (__bf16)fb.x, (__bf16)fb.y, (__bf16)fb.z, (__bf16)fb.w };
                int idx = (row * U + u0) ^ ((row & 7) << 3);
                *reinterpret_cast<v8bf*>(&buf[idx]) = hv;
            }
        } else {
            constexpr int PAIRS = U / 2;
            #pragma unroll
            for (int g = 0; g < SIT; ++g) {
                int gid = g * 256 + tid;
                int row = gid / PAIRS;
                int u0  = (gid % PAIRS) * 2;
                float f[2 * D];
                #pragma unroll
                for (int j = 0; j < D; ++j) {
                    float2 q = s2[g * D + j];
                    f[2 * j] = q.x; f[2 * j + 1] = q.y;
                }
                #pragma unroll
                for (int i = 0; i < D; ++i) {
                    int R = i * ROWS + row;
                    int idx = (R * U + u0) ^ ((R & 7) << 3);
                    v2bf h2 = { (__bf16)f[i], (__bf16)f[D + i] };
                    *reinterpret_cast<v2bf*>(&buf[idx]) = h2;
                }
            }
        }
    };

    v4f acc[MT][NPW];

    auto run_layer = [&](const unsigned short* __restrict__ wt,
                         const unsigned short* buf) {
        #pragma unroll
        for (int mt = 0; mt < MT; ++mt)
            #pragma unroll
            for (int nt = 0; nt < NPW; ++nt) {
                v4f z = {0.f, 0.f, 0.f, 0.f};
                acc[mt][nt] = z;
            }
        #pragma unroll
        for (int kt = 0; kt < KT; ++kt) {
            v8bf b[NPW];
            #pragma unroll
            for (int nt = 0; nt < NPW; ++nt) {
                int w = (wid * NPW + nt) * 16 + wcol;
                b[nt] = *reinterpret_cast<const v8bf*>(wt + w * U + kt * 32 + kcol);
            }
            #pragma unroll
            for (int mt = 0; mt < MT; ++mt) {
                int R = mt * 16 + wcol;
                int idx = (R * U + kt * 32 + kcol) ^ ((R & 7) << 3);
                v8bf a = *reinterpret_cast<const v8bf*>(&buf[idx]);
                #pragma unroll
                for (int nt = 0; nt < NPW; ++nt)
                    acc[mt][nt] = __builtin_amdgcn_mfma_f32_16x16x32_bf16(
                        a, b[nt], acc[mt][nt], 0, 0, 0);
            }
        }
    };

    // ---- prologue ----
    int t = bid;
    if (t >= NT) return;
    issue(t);
    unsigned short* cur = lds0;
    unsigned short* nxt = lds1;

    while (t < NT) {
        write_stage(cur);
        __syncthreads();                   // BAR1: stage visible

        int tn = t + NB;
        issue(tn < NT ? tn : t);           // loads fly across GEMM1+NA+GEMM2

        run_layer(wt0, cur);
        __syncthreads();                   // BAR2: x reads done

        // ---- norm-act -> cur (in place) ----
        #pragma unroll
        for (int nt = 0; nt < NPW; ++nt) {
            int w = (wid * NPW + nt) * 16 + wcol;
            #pragma unroll
            for (int h = 0; h < NR16; ++h) {
                #pragma unroll
                for (int r = 0; r < 4; ++r) {
                    float n;
                    if constexpr (D == 1) {
                        n = __builtin_fabsf(acc[h][nt][r]);
                    } else {
                        float s = 0.f;
                        #pragma unroll
                        for (int i = 0; i < D; ++i) {
                            float v = acc[i * NR16 + h][nt][r];
                            s += v * v;
                        }
                        n = __builtin_amdgcn_sqrtf(s);
                    }
                    float fac = phi_from_n(n);
                    int nr = h * 16 + g4 + r;
                    #pragma unroll
                    for (int i = 0; i < D; ++i) {
                        int R = i * ROWS + nr;
                        int idx = (R * U + w) ^ ((R & 7) << 3);
                        cur[idx] = bfbits(acc[i * NR16 + h][nt][r] * fac);
                    }
                }
            }
        }
        __syncthreads();                   // BAR3: H visible

        run_layer(wt1, cur);

        // ---- store fp32 at out[n][OFF + w*D + i] ----
        #pragma unroll
        for (int nt = 0; nt < NPW; ++nt) {
            int w = (wid * NPW + nt) * 16 + wcol;
            #pragma unroll
            for (int h = 0; h < NR16; ++h) {
                #pragma unroll
                for (int r = 0; r < 4; ++r) {
                    int n = t * ROWS + h * 16 + g4 + r;
                    float* po = out + (long)n * 960 + OFF + w * D;
                    #pragma unroll
                    for (int i = 0; i < D; ++i)
                        po[i] = acc[i * NR16 + h][nt][r];
                }
            }
        }

        t = tn;
        unsigned short* tmp = cur; cur = nxt; nxt = tmp;
    }
}

// --- merged persistent kernel: contiguous type ranges ------------------------
// bid 0..287   : l=0 (ROWS=32, 2048 tiles)
// bid 288..575 : l=1 (ROWS=16, 4096 tiles)
// bid 576..767 : l=2 (ROWS=16, 4096 tiles)
__global__ __launch_bounds__(256, 3) void fused_all(
    const float* __restrict__ x,
    const unsigned short* __restrict__ ws,
    float* __restrict__ out)
{
    __shared__ unsigned short lds[2][8192];   // 2 x 16 KB
    int bid = blockIdx.x;
    if (bid < 288)
        irrep_pipe<256, 1,   0, 32>(x, ws + 0,     ws + 86016,  out,
                                    lds[0], lds[1], bid, 288);
    else if (bid < 576)
        irrep_pipe<128, 3, 256, 16>(x, ws + 65536, ws + 151552, out,
                                    lds[0], lds[1], bid - 288, 288);
    else
        irrep_pipe< 64, 5, 640, 16>(x, ws + 81920, ws + 167936, out,
                                    lds[0], lds[1], bid - 576, 192);
}

extern "C" void kernel_launch(void* const* d_in, const int* in_sizes, int n_in,
                              void* d_out, int out_size, void* d_ws, size_t ws_size,
                              hipStream_t stream)
{
    const float* x  = (const float*)d_in[0];
    const float* W0 = (const float*)d_in[1];  // 256x256
    const float* W1 = (const float*)d_in[2];  // 128x128
    const float* W2 = (const float*)d_in[3];  // 64x64
    const float* W3 = (const float*)d_in[4];  // 256x256
    const float* W4 = (const float*)d_in[5];  // 128x128
    const float* W5 = (const float*)d_in[6];  // 64x64
    unsigned short* ws = (unsigned short*)d_ws;   // 344064 B of bf16 WT
    float* out = (float*)d_out;

    wt_prep<<<672, 256, 0, stream>>>(W0, W1, W2, W3, W4, W5, ws);
    fused_all<<<768, 256, 0, stream>>>(x, ws, out);
}

// Round 13
// 233.723 us; speedup vs baseline: 1.1431x; 1.1431x over previous
//
#include <hip/hip_runtime.h>

// irreps: 256x0e + 128x1e + 64x2e ; x row = 960 fp32
// R13: l=0 -> persistent blocks + global_load_lds single-buffer pipeline:
//   xbuf [32][256] fp32 staged by gload_lds (LDS linear, GLOBAL source
//   pre-swizzled per 16B chunk: q ^= row&7; A-read applies same XOR).
//   Issue stage(t+NB) right after GEMM1's barrier; the only vmcnt(0) drain
//   is at loop end (after normact+GEMM2+store) -> HBM latency fully hidden,
//   ZERO register staging (R4/R6/R12 all spilled register staging).
//   Raw s_barrier / counted waitcnt via inline asm -- __syncthreads would
//   drain vmcnt immediately after the issue and kill the overlap.
// l=1/l=2: R10 structure verbatim (LDS-staged bf16, __syncthreads).

typedef __bf16 v8bf  __attribute__((ext_vector_type(8)));
typedef __bf16 v2bf  __attribute__((ext_vector_type(2)));
typedef float  v4f   __attribute__((ext_vector_type(4)));

__device__ __forceinline__ unsigned short bfbits(float x) {
    __bf16 h = (__bf16)x;
    return __builtin_bit_cast(unsigned short, h);
}

// Phi(n) = 0.5*(1+erf(n/sqrt(2))) = gelu(n)/n, n>=0.  A&S 7.1.26.
__device__ __forceinline__ float phi_from_n(float n) {
    float z = n * 0.70710678118654752f;
    float t = __builtin_amdgcn_rcpf(fmaf(0.3275911f, z, 1.0f));
    float p = t * fmaf(t, fmaf(t, fmaf(t, fmaf(t, 1.061405429f, -1.453152027f),
                                       1.421413741f), -0.284496736f), 0.254829592f);
    float e = __builtin_amdgcn_exp2f(z * z * -1.4426950408889634f);
    return fmaf(p * e, -0.5f, 1.0f);
}

// --- pre-pass: W[u][w] fp32 -> WT[w][u] bf16, scaled by 1/sqrt(mul_in) -------
__global__ __launch_bounds__(256) void wt_prep(
    const float* __restrict__ w0, const float* __restrict__ w1,
    const float* __restrict__ w2, const float* __restrict__ w3,
    const float* __restrict__ w4, const float* __restrict__ w5,
    unsigned short* __restrict__ out)
{
    int t = blockIdx.x * 256 + threadIdx.x;
    if (t >= 172032) return;
    int s = (t < 65536) ? 0 : (t < 81920) ? 1 : (t < 86016) ? 2
          : (t < 151552) ? 3 : (t < 167936) ? 4 : 5;
    int base = (s == 0) ? 0 : (s == 1) ? 65536 : (s == 2) ? 81920
             : (s == 3) ? 86016 : (s == 4) ? 151552 : 167936;
    int lg   = (s == 0 || s == 3) ? 8 : (s == 1 || s == 4) ? 7 : 6;
    float scl = (s == 0 || s == 3) ? 0.0625f
              : (s == 1 || s == 4) ? 0.08838834764831845f : 0.125f;
    const float* p = (s == 0) ? w0 : (s == 1) ? w1 : (s == 2) ? w2
                   : (s == 3) ? w3 : (s == 4) ? w4 : w5;
    int loc = t - base;
    int w = loc >> lg;
    int u = loc & ((1 << lg) - 1);
    out[t] = bfbits(p[(u << lg) + w] * scl);
}

// --- l=0 persistent pipelined worker -----------------------------------------
__device__ __forceinline__ void l0_pipe(
    const float* __restrict__ x,
    const unsigned short* __restrict__ wt0,
    const unsigned short* __restrict__ wt1,
    float* __restrict__ out,
    float* xbuf,                 // [32][256] fp32, 16B-chunk source-swizzled
    unsigned short* hbuf,        // [32][256] bf16, element-XOR swizzled
    int bid, int NB)
{
    constexpr int NT = 2048;
    const int tid  = threadIdx.x;
    const int lane = tid & 63;
    const int wid  = tid >> 6;
    const int wcol = lane & 15;
    const int oct  = lane >> 4;
    const int kcol = oct << 3;    // float offset in k-32
    const int g4   = oct << 2;

    // stage tile -> xbuf via gload_lds; LDS linear, global chunk pre-swizzled
    auto stage = [&](int tile) {
        #pragma unroll
        for (int o = 0; o < 8; ++o) {
            int r = wid + o * 4;                          // wave-uniform row
            const float* src = x + (long)(tile * 32 + r) * 960
                             + ((lane ^ (r & 7)) << 2);   // swizzled 16B chunk
            float* dst = xbuf + r * 256;                  // +lane*16B implicit
            __builtin_amdgcn_global_load_lds(
                (const __attribute__((address_space(1))) void*)(const void*)src,
                (__attribute__((address_space(3))) void*)(void*)dst, 16, 0, 0);
        }
    };

    int t = bid;
    stage(t);
    asm volatile("s_waitcnt vmcnt(0)\ns_barrier" ::: "memory");

    while (t < NT) {
        v4f acc[2][4];
        #pragma unroll
        for (int mt = 0; mt < 2; ++mt)
            #pragma unroll
            for (int nt = 0; nt < 4; ++nt) {
                v4f z = {0.f, 0.f, 0.f, 0.f};
                acc[mt][nt] = z;
            }

        // ---- GEMM1: A = fp32 from xbuf (swizzled read + cvt), B = WT0 ----
        #pragma unroll
        for (int kt = 0; kt < 8; ++kt) {
            v8bf b[4];
            #pragma unroll
            for (int nt = 0; nt < 4; ++nt) {
                int w = (wid * 4 + nt) * 16 + wcol;
                b[nt] = *reinterpret_cast<const v8bf*>(wt0 + w * 256 + kt * 32 + kcol);
            }
            #pragma unroll
            for (int mt = 0; mt < 2; ++mt) {
                int r  = mt * 16 + wcol;
                int c0 = kt * 8 + oct * 2;                // 16B chunk in row
                const float4* base = reinterpret_cast<const float4*>(xbuf + r * 256);
                float4 fa = base[c0 ^ (r & 7)];
                float4 fb = base[(c0 + 1) ^ (r & 7)];
                v8bf a = { (__bf16)fa.x, (__bf16)fa.y, (__bf16)fa.z, (__bf16)fa.w,
                           (__bf16)fb.x, (__bf16)fb.y, (__bf16)fb.z, (__bf16)fb.w };
                #pragma unroll
                for (int nt = 0; nt < 4; ++nt)
                    acc[mt][nt] = __builtin_amdgcn_mfma_f32_16x16x32_bf16(
                        a, b[nt], acc[mt][nt], 0, 0, 0);
            }
        }

        asm volatile("s_barrier" ::: "memory");    // x dead (no vmcnt drain)

        int tn = t + NB;
        if (tn < NT) stage(tn);                    // loads fly across NA+GEMM2
        __builtin_amdgcn_sched_barrier(0);

        // ---- norm-act -> hbuf ----
        #pragma unroll
        for (int nt = 0; nt < 4; ++nt) {
            int w = (wid * 4 + nt) * 16 + wcol;
            #pragma unroll
            for (int h = 0; h < 2; ++h) {
                #pragma unroll
                for (int r = 0; r < 4; ++r) {
                    float v   = acc[h][nt][r];
                    float fac = phi_from_n(__builtin_fabsf(v));
                    int R   = h * 16 + g4 + r;
                    int idx = (R * 256 + w) ^ ((R & 7) << 3);
                    hbuf[idx] = bfbits(v * fac);
                }
            }
        }
        asm volatile("s_waitcnt lgkmcnt(0)\ns_barrier" ::: "memory");  // H ready
        __builtin_amdgcn_sched_barrier(0);

        // ---- GEMM2: A = H from hbuf, B = WT1 ----
        #pragma unroll
        for (int mt = 0; mt < 2; ++mt)
            #pragma unroll
            for (int nt = 0; nt < 4; ++nt) {
                v4f z = {0.f, 0.f, 0.f, 0.f};
                acc[mt][nt] = z;
            }
        #pragma unroll
        for (int kt = 0; kt < 8; ++kt) {
            v8bf b[4];
            #pragma unroll
            for (int nt = 0; nt < 4; ++nt) {
                int w = (wid * 4 + nt) * 16 + wcol;
                b[nt] = *reinterpret_cast<const v8bf*>(wt1 + w * 256 + kt * 32 + kcol);
            }
            #pragma unroll
            for (int mt = 0; mt < 2; ++mt) {
                int R   = mt * 16 + wcol;
                int idx = (R * 256 + kt * 32 + kcol) ^ ((R & 7) << 3);
                v8bf a = *reinterpret_cast<const v8bf*>(&hbuf[idx]);
                #pragma unroll
                for (int nt = 0; nt < 4; ++nt)
                    acc[mt][nt] = __builtin_amdgcn_mfma_f32_16x16x32_bf16(
                        a, b[nt], acc[mt][nt], 0, 0, 0);
            }
        }

        // ---- store fp32 ----
        #pragma unroll
        for (int nt = 0; nt < 4; ++nt) {
            int w = (wid * 4 + nt) * 16 + wcol;
            #pragma unroll
            for (int h = 0; h < 2; ++h) {
                #pragma unroll
                for (int r = 0; r < 4; ++r) {
                    int n = t * 32 + h * 16 + g4 + r;
                    out[(long)n * 960 + w] = acc[h][nt][r];
                }
            }
        }

        t = tn;
        // drain stage loads (+store acks) and sync before next GEMM1
        asm volatile("s_waitcnt vmcnt(0)\ns_barrier" ::: "memory");
    }
    asm volatile("s_waitcnt vmcnt(0)" ::: "memory");   // no loads leak past exit
}

// --- l=1 / l=2 worker (R10 structure, 32-row tiles) --------------------------
template<int U, int D, int OFF>
__device__ __forceinline__ void irrep_block(
    const float* __restrict__ x,
    const unsigned short* __restrict__ wt0,
    const unsigned short* __restrict__ wt1,
    float* __restrict__ out,
    unsigned short* __restrict__ lds,
    int tile)
{
    constexpr int ROWS = 32;
    constexpr int MT   = (ROWS * D) / 16;
    constexpr int NPW  = U / 64;
    constexpr int KT   = U / 32;
    constexpr int NR16 = ROWS / 16;

    const int tid  = threadIdx.x;
    const int lane = tid & 63;
    const int wid  = tid >> 6;
    const int row0 = tile * ROWS;
    const int wcol = lane & 15;
    const int kcol = (lane >> 4) << 3;
    const int g4   = (lane >> 4) << 2;

    constexpr int PAIRS = U / 2;
    #pragma unroll
    for (int g = 0; g < (ROWS * PAIRS) / 256; ++g) {
        int gid = g * 256 + tid;
        int row = gid / PAIRS;
        int u0  = (gid % PAIRS) * 2;
        const float2* p = reinterpret_cast<const float2*>(
            x + (long)(row0 + row) * 960 + OFF + u0 * D);
        float f[2 * D];
        #pragma unroll
        for (int j = 0; j < D; ++j) { float2 q = p[j]; f[2*j] = q.x; f[2*j+1] = q.y; }
        #pragma unroll
        for (int i = 0; i < D; ++i) {
            int R = i * ROWS + row;
            int idx = (R * U + u0) ^ ((R & 7) << 3);
            v2bf h2 = { (__bf16)f[i], (__bf16)f[D + i] };
            *reinterpret_cast<v2bf*>(&lds[idx]) = h2;
        }
    }

    v4f acc[MT][NPW];
    v8bf bpre[NPW];

    auto issueB = [&](const unsigned short* __restrict__ wt, int kt) {
        #pragma unroll
        for (int nt = 0; nt < NPW; ++nt) {
            int w = (wid * NPW + nt) * 16 + wcol;
            bpre[nt] = *reinterpret_cast<const v8bf*>(wt + w * U + kt * 32 + kcol);
        }
    };

    auto run_layer = [&](const unsigned short* __restrict__ wt) {
        #pragma unroll
        for (int mt = 0; mt < MT; ++mt)
            #pragma unroll
            for (int nt = 0; nt < NPW; ++nt) {
                v4f z = {0.f, 0.f, 0.f, 0.f};
                acc[mt][nt] = z;
            }
        #pragma unroll
        for (int kt = 0; kt < KT; ++kt) {
            v8bf bcur[NPW];
            #pragma unroll
            for (int nt = 0; nt < NPW; ++nt) bcur[nt] = bpre[nt];
            if (kt + 1 < KT) issueB(wt, kt + 1);
            #pragma unroll
            for (int mt = 0; mt < MT; ++mt) {
                int R = mt * 16 + wcol;
                int idx = (R * U + kt * 32 + kcol) ^ ((R & 7) << 3);
                v8bf a = *reinterpret_cast<const v8bf*>(&lds[idx]);
                #pragma unroll
                for (int nt = 0; nt < NPW; ++nt)
                    acc[mt][nt] = __builtin_amdgcn_mfma_f32_16x16x32_bf16(
                        a, bcur[nt], acc[mt][nt], 0, 0, 0);
            }
        }
    };

    issueB(wt0, 0);
    __syncthreads();

    run_layer(wt0);
    __syncthreads();

    issueB(wt1, 0);

    #pragma unroll
    for (int nt = 0; nt < NPW; ++nt) {
        int w = (wid * NPW + nt) * 16 + wcol;
        #pragma unroll
        for (int h = 0; h < NR16; ++h) {
            #pragma unroll
            for (int r = 0; r < 4; ++r) {
                float s = 0.f;
                #pragma unroll
                for (int i = 0; i < D; ++i) {
                    float v = acc[i * NR16 + h][nt][r];
                    s += v * v;
                }
                float fac = phi_from_n(__builtin_amdgcn_sqrtf(s));
                int nr = h * 16 + g4 + r;
                #pragma unroll
                for (int i = 0; i < D; ++i) {
                    int R = i * ROWS + nr;
                    int idx = (R * U + w) ^ ((R & 7) << 3);
                    lds[idx] = bfbits(acc[i * NR16 + h][nt][r] * fac);
                }
            }
        }
    }
    __syncthreads();

    run_layer(wt1);

    #pragma unroll
    for (int nt = 0; nt < NPW; ++nt) {
        int w = (wid * NPW + nt) * 16 + wcol;
        #pragma unroll
        for (int h = 0; h < NR16; ++h) {
            #pragma unroll
            for (int r = 0; r < 4; ++r) {
                int n = row0 + h * 16 + g4 + r;
                float* po = out + (long)n * 960 + OFF + w * D;
                #pragma unroll
                for (int i = 0; i < D; ++i)
                    po[i] = acc[i * NR16 + h][nt][r];
            }
        }
    }
}

// --- merged kernel ------------------------------------------------------------
// bid 0..383     : l=0 persistent pipelined (2048 tiles, stride 384)
// bid 384..2431  : l=1, 32-row tiles
// bid 2432..4479 : l=2, 32-row tiles
__global__ __launch_bounds__(256, 3) void fused_all(
    const float* __restrict__ x,
    const unsigned short* __restrict__ ws,
    float* __restrict__ out)
{
    __shared__ __align__(16) unsigned char smem[49152];   // 48 KB
    int bid = blockIdx.x;
    if (bid < 384)
        l0_pipe(x, ws + 0, ws + 86016, out,
                reinterpret_cast<float*>(smem),
                reinterpret_cast<unsigned short*>(smem + 32768),
                bid, 384);
    else if (bid < 2432)
        irrep_block<128, 3, 256>(x, ws + 65536, ws + 151552, out,
                                 reinterpret_cast<unsigned short*>(smem), bid - 384);
    else
        irrep_block< 64, 5, 640>(x, ws + 81920, ws + 167936, out,
                                 reinterpret_cast<unsigned short*>(smem), bid - 2432);
}

extern "C" void kernel_launch(void* const* d_in, const int* in_sizes, int n_in,
                              void* d_out, int out_size, void* d_ws, size_t ws_size,
                              hipStream_t stream)
{
    const float* x  = (const float*)d_in[0];
    const float* W0 = (const float*)d_in[1];  // 256x256
    const float* W1 = (const float*)d_in[2];  // 128x128
    const float* W2 = (const float*)d_in[3];  // 64x64
    const float* W3 = (const float*)d_in[4];  // 256x256
    const float* W4 = (const float*)d_in[5];  // 128x128
    const float* W5 = (const float*)d_in[6];  // 64x64
    unsigned short* ws = (unsigned short*)d_ws;   // 344064 B of bf16 WT
    float* out = (float*)d_out;

    wt_prep<<<672, 256, 0, stream>>>(W0, W1, W2, W3, W4, W5, ws);
    fused_all<<<4480, 256, 0, stream>>>(x, ws, out);
}

// Round 14
// 134.261 us; speedup vs baseline: 1.9899x; 1.7408x over previous
//
#include <hip/hip_runtime.h>

// irreps: 256x0e + 128x1e + 64x2e ; x row = 960 fp32
// R14 = R10 template (best: 141.7us) with tiles grown one step along the
// measured gradient (R2->R5 gained, R9 shrink lost):
//   l=0: 128-row tiles (64 KB LDS, B:MFMA 1:8)
//   l=1:  64-row tiles (48 KB LDS, 1:6)
//   l=2:  64-row tiles (40 KB LDS, 1:20)
// Non-persistent, one tile/block, 3 barriers/tile, XOR-swizzled LDS,
// distance-1 B prefetch. __launch_bounds__(256,2) -> 2 blocks/CU, 256 VGPR cap.

typedef __bf16 v8bf  __attribute__((ext_vector_type(8)));
typedef __bf16 v2bf  __attribute__((ext_vector_type(2)));
typedef float  v4f   __attribute__((ext_vector_type(4)));

__device__ __forceinline__ unsigned short bfbits(float x) {
    __bf16 h = (__bf16)x;
    return __builtin_bit_cast(unsigned short, h);
}

// Phi(n) = 0.5*(1+erf(n/sqrt(2))) = gelu(n)/n, n>=0.  A&S 7.1.26.
__device__ __forceinline__ float phi_from_n(float n) {
    float z = n * 0.70710678118654752f;
    float t = __builtin_amdgcn_rcpf(fmaf(0.3275911f, z, 1.0f));
    float p = t * fmaf(t, fmaf(t, fmaf(t, fmaf(t, 1.061405429f, -1.453152027f),
                                       1.421413741f), -0.284496736f), 0.254829592f);
    float e = __builtin_amdgcn_exp2f(z * z * -1.4426950408889634f);
    return fmaf(p * e, -0.5f, 1.0f);
}

// --- pre-pass: W[u][w] fp32 -> WT[w][u] bf16, scaled by 1/sqrt(mul_in) -------
__global__ __launch_bounds__(256) void wt_prep(
    const float* __restrict__ w0, const float* __restrict__ w1,
    const float* __restrict__ w2, const float* __restrict__ w3,
    const float* __restrict__ w4, const float* __restrict__ w5,
    unsigned short* __restrict__ out)
{
    int t = blockIdx.x * 256 + threadIdx.x;
    if (t >= 172032) return;
    int s = (t < 65536) ? 0 : (t < 81920) ? 1 : (t < 86016) ? 2
          : (t < 151552) ? 3 : (t < 167936) ? 4 : 5;
    int base = (s == 0) ? 0 : (s == 1) ? 65536 : (s == 2) ? 81920
             : (s == 3) ? 86016 : (s == 4) ? 151552 : 167936;
    int lg   = (s == 0 || s == 3) ? 8 : (s == 1 || s == 4) ? 7 : 6;
    float scl = (s == 0 || s == 3) ? 0.0625f
              : (s == 1 || s == 4) ? 0.08838834764831845f : 0.125f;
    const float* p = (s == 0) ? w0 : (s == 1) ? w1 : (s == 2) ? w2
                   : (s == 3) ? w3 : (s == 4) ? w4 : w5;
    int loc = t - base;
    int w = loc >> lg;
    int u = loc & ((1 << lg) - 1);
    out[t] = bfbits(p[(u << lg) + w] * scl);
}

// --- per-irrep worker (ROWS-row tile) ----------------------------------------
// LDS: bf16 planes [i][n(ROWS)][u(U)], XOR-swizzled idx ^= (R&7)<<3, R=i*ROWS+n.
template<int U, int D, int OFF, int ROWS>
__device__ __forceinline__ void irrep_block(
    const float* __restrict__ x,
    const unsigned short* __restrict__ wt0,
    const unsigned short* __restrict__ wt1,
    float* __restrict__ out,
    unsigned short* __restrict__ lds,
    int tile)
{
    constexpr int MT   = (ROWS * D) / 16;   // m-tiles
    constexpr int NPW  = U / 64;            // n-tiles per wave (4 waves split n)
    constexpr int KT   = U / 32;            // k-steps
    constexpr int NR16 = ROWS / 16;         // 16-row groups per i-plane
    static_assert(ROWS * D * U <= 32768, "LDS overflow");

    const int tid  = threadIdx.x;
    const int lane = tid & 63;
    const int wid  = tid >> 6;
    const int row0 = tile * ROWS;
    const int wcol = lane & 15;
    const int kcol = (lane >> 4) << 3;
    const int g4   = (lane >> 4) << 2;

    // ---- stage x -> LDS bf16, de-interleaved [i*ROWS+n][u] ----
    if constexpr (D == 1) {
        #pragma unroll
        for (int o = 0; o < (ROWS * (U / 8)) / 256; ++o) {
            int oct = o * 256 + tid;
            int row = oct / (U / 8);
            int u0  = (oct % (U / 8)) * 8;
            const float4* p =
                reinterpret_cast<const float4*>(x + (long)(row0 + row) * 960 + OFF + u0);
            float4 fa = p[0], fb = p[1];
            v8bf hv = { (__bf16)fa.x, (__bf16)fa.y, (__bf16)fa.z, (__bf16)fa.w,
                        (__bf16)fb.x, (__bf16)fb.y, (__bf16)fb.z, (__bf16)fb.w };
            int idx = (row * U + u0) ^ ((row & 7) << 3);
            *reinterpret_cast<v8bf*>(&lds[idx]) = hv;
        }
    } else {
        constexpr int PAIRS = U / 2;
        #pragma unroll
        for (int g = 0; g < (ROWS * PAIRS) / 256; ++g) {
            int gid = g * 256 + tid;
            int row = gid / PAIRS;
            int u0  = (gid % PAIRS) * 2;
            const float2* p = reinterpret_cast<const float2*>(
                x + (long)(row0 + row) * 960 + OFF + u0 * D);
            float f[2 * D];
            #pragma unroll
            for (int j = 0; j < D; ++j) { float2 q = p[j]; f[2*j] = q.x; f[2*j+1] = q.y; }
            #pragma unroll
            for (int i = 0; i < D; ++i) {
                int R = i * ROWS + row;
                int idx = (R * U + u0) ^ ((R & 7) << 3);
                v2bf h2 = { (__bf16)f[i], (__bf16)f[D + i] };
                *reinterpret_cast<v2bf*>(&lds[idx]) = h2;
            }
        }
    }

    v4f acc[MT][NPW];
    v8bf bpre[NPW];

    auto issueB = [&](const unsigned short* __restrict__ wt, int kt) {
        #pragma unroll
        for (int nt = 0; nt < NPW; ++nt) {
            int w = (wid * NPW + nt) * 16 + wcol;
            bpre[nt] = *reinterpret_cast<const v8bf*>(wt + w * U + kt * 32 + kcol);
        }
    };

    auto run_layer = [&](const unsigned short* __restrict__ wt) {
        #pragma unroll
        for (int mt = 0; mt < MT; ++mt)
            #pragma unroll
            for (int nt = 0; nt < NPW; ++nt) {
                v4f z = {0.f, 0.f, 0.f, 0.f};
                acc[mt][nt] = z;
            }
        #pragma unroll
        for (int kt = 0; kt < KT; ++kt) {
            v8bf bcur[NPW];
            #pragma unroll
            for (int nt = 0; nt < NPW; ++nt) bcur[nt] = bpre[nt];
            if (kt + 1 < KT) issueB(wt, kt + 1);
            #pragma unroll
            for (int mt = 0; mt < MT; ++mt) {
                int R = mt * 16 + wcol;
                int idx = (R * U + kt * 32 + kcol) ^ ((R & 7) << 3);
                v8bf a = *reinterpret_cast<const v8bf*>(&lds[idx]);
                #pragma unroll
                for (int nt = 0; nt < NPW; ++nt)
                    acc[mt][nt] = __builtin_amdgcn_mfma_f32_16x16x32_bf16(
                        a, bcur[nt], acc[mt][nt], 0, 0, 0);
            }
        }
    };

    issueB(wt0, 0);      // L2 round trip overlaps staging + barrier skew
    __syncthreads();     // stage visible

    run_layer(wt0);
    __syncthreads();     // all layer-1 LDS reads done before H overwrites x

    issueB(wt1, 0);      // layer-2 kstep-0 B flies under normact

    // ---- norm-act: acc[i*NR16+h][nt][r] holds component i of row (h*16+g4+r) ----
    #pragma unroll
    for (int nt = 0; nt < NPW; ++nt) {
        int w = (wid * NPW + nt) * 16 + wcol;
        #pragma unroll
        for (int h = 0; h < NR16; ++h) {
            #pragma unroll
            for (int r = 0; r < 4; ++r) {
                float n;
                if constexpr (D == 1) {
                    n = __builtin_fabsf(acc[h][nt][r]);
                } else {
                    float s = 0.f;
                    #pragma unroll
                    for (int i = 0; i < D; ++i) {
                        float v = acc[i * NR16 + h][nt][r];
                        s += v * v;
                    }
                    n = __builtin_amdgcn_sqrtf(s);
                }
                float fac = phi_from_n(n);
                int nr = h * 16 + g4 + r;
                #pragma unroll
                for (int i = 0; i < D; ++i) {
                    int R = i * ROWS + nr;
                    int idx = (R * U + w) ^ ((R & 7) << 3);
                    lds[idx] = bfbits(acc[i * NR16 + h][nt][r] * fac);
                }
            }
        }
    }
    __syncthreads();     // H visible

    run_layer(wt1);

    // ---- store fp32 at out[n][OFF + w*D + i]; lanes -> consecutive w ----
    #pragma unroll
    for (int nt = 0; nt < NPW; ++nt) {
        int w = (wid * NPW + nt) * 16 + wcol;
        #pragma unroll
        for (int h = 0; h < NR16; ++h) {
            #pragma unroll
            for (int r = 0; r < 4; ++r) {
                int n = row0 + h * 16 + g4 + r;
                float* po = out + (long)n * 960 + OFF + w * D;
                #pragma unroll
                for (int i = 0; i < D; ++i)
                    po[i] = acc[i * NR16 + h][nt][r];
            }
        }
    }
}

// --- merged kernel: contiguous type ranges ------------------------------------
// bid 0..511     : l=0, 128-row tiles
// bid 512..1535  : l=1,  64-row tiles
// bid 1536..2559 : l=2,  64-row tiles
__global__ __launch_bounds__(256, 2) void fused_all(
    const float* __restrict__ x,
    const unsigned short* __restrict__ ws,
    float* __restrict__ out)
{
    __shared__ unsigned short lds[32768];   // 64 KB (max over the 3 types)
    int bid = blockIdx.x;
    if (bid < 512)
        irrep_block<256, 1,   0, 128>(x, ws + 0,     ws + 86016,  out, lds, bid);
    else if (bid < 1536)
        irrep_block<128, 3, 256,  64>(x, ws + 65536, ws + 151552, out, lds, bid - 512);
    else
        irrep_block< 64, 5, 640,  64>(x, ws + 81920, ws + 167936, out, lds, bid - 1536);
}

extern "C" void kernel_launch(void* const* d_in, const int* in_sizes, int n_in,
                              void* d_out, int out_size, void* d_ws, size_t ws_size,
                              hipStream_t stream)
{
    const float* x  = (const float*)d_in[0];
    const float* W0 = (const float*)d_in[1];  // 256x256
    const float* W1 = (const float*)d_in[2];  // 128x128
    const float* W2 = (const float*)d_in[3];  // 64x64
    const float* W3 = (const float*)d_in[4];  // 256x256
    const float* W4 = (const float*)d_in[5];  // 128x128
    const float* W5 = (const float*)d_in[6];  // 64x64
    unsigned short* ws = (unsigned short*)d_ws;   // 344064 B of bf16 WT
    float* out = (float*)d_out;

    wt_prep<<<672, 256, 0, stream>>>(W0, W1, W2, W3, W4, W5, ws);
    fused_all<<<2560, 256, 0, stream>>>(x, ws, out);
}